// Round 11
// baseline (663.811 us; speedup 1.0000x reference)
//
#include <hip/hip_runtime.h>
#include <hip/hip_cooperative_groups.h>
#include <cstdint>

namespace cg = cooperative_groups;

#define N_NODES 100000
#define N_EDGES 3200000
#define SPAN    256                       // nodes per bucket
#define SHIFT   8
#define NB      391                       // buckets = ceil(N_NODES/SPAN)
#define NBLK    256                       // one block per CU
#define BTH     1024
#define CHUNK   12500                     // N_EDGES / NBLK exactly
#define NITER   13                        // ceil(CHUNK/BTH)
#define PREF_W  (NB + 1)                  // 392

// ---------------------------------------------------------------------------
// Single cooperative kernel. Phases (grid.sync between):
//  0: dtype detect, prep u = vm*e^{i va}, base = (pg-pd,qg-qd), zero d_out
//  A: per-block LDS counting sort of its 12500 edges by src bucket;
//     record rc.x = vr | lid(8b), rc.y = vi | bk(9b); write prefix row
//  B: block j computes global bases for bucket j (+ j+256): S = sum of
//     prefT[j][*] (edges in buckets < j, all blocks), scan of per-block counts
//  C: scatter s_rec (still in LDS!) to globally bucket-sorted gsorted[]
//  D: bucket b = contiguous region [S_b, S_b+n_b): streaming read, LDS f32
//     accumulate (4 replicas), per-node loss, one atomic per block
// ---------------------------------------------------------------------------
__global__ __launch_bounds__(BTH)
void fused_kernel(const float* __restrict__ pred,
                  const float* __restrict__ target,
                  const void* __restrict__ edge_index,
                  const float2* __restrict__ edge_attr,
                  const void* __restrict__ mask,
                  float2* __restrict__ u_tab,
                  float2* __restrict__ base_pq,
                  uint16_t* __restrict__ prefT,     // [PREF_W][NBLK]
                  uint32_t* __restrict__ base_gT,   // [NBLK][NB]
                  uint2* __restrict__ gsorted,      // [N_EDGES]
                  float* __restrict__ d_out, int out_size) {
    __shared__ uint2 s_rec[CHUNK];          // 100 KB
    __shared__ uint32_t s_cnt[NB];          // counts -> ranks -> base_row
    __shared__ uint32_t s_pref[PREF_W];
    __shared__ uint32_t s_wsum[16], s_woff[16];
    __shared__ float2 s_acc[4][SPAN];       // 8 KB
    __shared__ float s_part[4];
    __shared__ uint32_t s_tS[2], s_tN[2];
    __shared__ int s_mask8, s_i64;

    cg::grid_group grid = cg::this_grid();
    const int tid = threadIdx.x;
    const int lane = tid & 63, wid = tid >> 6;
    const int blk = blockIdx.x;

    // ---------------- phase 0: detect + prep ----------------
    if (tid < 64) {
        uint32_t w  = ((const uint32_t*)mask)[tid];
        uint32_t w2 = ((const uint32_t*)edge_index)[tid];
        unsigned long long mA = __ballot((w & 0xFFFFFF00u) != 0u);
        unsigned long long mB = __ballot((tid & 1) && (w2 != 0u));
        if (tid == 0) { s_mask8 = (mA != 0ull); s_i64 = (mB == 0ull); }
    }
    if (blk == 0 && tid == 0)
        for (int k = 0; k < out_size; ++k) d_out[k] = 0.0f;
    __syncthreads();

    {
        int i = blk * BTH + tid;
        if (i < N_NODES) {
            const float2* p2 = (const float2*)pred;
            const float2* t2 = (const float2*)target;
            float2 pa = p2[3 * i], pb = p2[3 * i + 1], pc = p2[3 * i + 2];
            float2 ta = t2[3 * i], tb = t2[3 * i + 1], tc = t2[3 * i + 2];
            float pr[6] = {pa.x, pa.y, pb.x, pb.y, pc.x, pc.y};
            float tg[6] = {ta.x, ta.y, tb.x, tb.y, tc.x, tc.y};
            int mk[6];
            if (s_mask8) {
                const uint16_t* mu = (const uint16_t*)mask;
                uint16_t m0 = mu[3 * i], m1 = mu[3 * i + 1], m2 = mu[3 * i + 2];
                mk[0] = m0 & 0xFF; mk[1] = m0 >> 8;
                mk[2] = m1 & 0xFF; mk[3] = m1 >> 8;
                mk[4] = m2 & 0xFF; mk[5] = m2 >> 8;
            } else {
                const int2* mi = (const int2*)mask;
                int2 m0 = mi[3 * i], m1 = mi[3 * i + 1], m2 = mi[3 * i + 2];
                mk[0] = m0.x; mk[1] = m0.y; mk[2] = m1.x;
                mk[3] = m1.y; mk[4] = m2.x; mk[5] = m2.y;
            }
            float tp[6];
            #pragma unroll
            for (int j = 0; j < 6; ++j) tp[j] = mk[j] ? pr[j] : tg[j];
            float s, c;
            sincosf(tp[1], &s, &c);
            u_tab[i]   = make_float2(tp[0] * c, tp[0] * s);
            base_pq[i] = make_float2(tp[2] - tp[4], tp[3] - tp[5]);
        }
    }
    __threadfence();
    grid.sync();

    // ---------------- phase A: histogram + sort ----------------
    for (int b = tid; b < NB; b += BTH) s_cnt[b] = 0u;
    __syncthreads();
    const bool is64 = (s_i64 != 0);
    const long long ebase = (long long)blk * CHUNK;

    uint32_t src_r[NITER];
    #pragma unroll
    for (int it = 0; it < NITER; ++it) {
        int j = it * BTH + tid;
        uint32_t s = 0u;
        if (j < CHUNK) {
            long long e = ebase + j;
            s = is64 ? (uint32_t)((const unsigned long long*)edge_index)[e]
                     : ((const uint32_t*)edge_index)[e];
            atomicAdd(&s_cnt[s >> SHIFT], 1u);
        }
        src_r[it] = s;
    }
    __syncthreads();

    // two-level shfl scan over 1024 slots (NB live) -> s_pref
    {
        uint32_t v0 = (tid < NB) ? s_cnt[tid] : 0u;
        uint32_t x = v0;
        #pragma unroll
        for (int off = 1; off < 64; off <<= 1) {
            uint32_t y = (uint32_t)__shfl_up((int)x, off, 64);
            if (lane >= off) x += y;
        }
        if (lane == 63) s_wsum[wid] = x;
        __syncthreads();
        if (tid < 16) {
            uint32_t w0 = s_wsum[tid];
            uint32_t xx = w0;
            #pragma unroll
            for (int off = 1; off < 16; off <<= 1) {
                uint32_t y = (uint32_t)__shfl_up((int)xx, off, 64);
                if (tid >= off) xx += y;
            }
            s_woff[tid] = xx - w0;
        }
        __syncthreads();
        uint32_t incl = x + s_woff[wid];
        if (tid < NB) s_pref[tid + 1] = incl;
        if (tid == 0) s_pref[0] = 0u;
        if (tid < NB) s_cnt[tid] = 0u;     // reuse as running rank
        __syncthreads();
    }

    #pragma unroll
    for (int it = 0; it < NITER; ++it) {
        int j = it * BTH + tid;
        if (j < CHUNK) {
            long long e = ebase + j;
            uint32_t dst = is64
                ? (uint32_t)((const unsigned long long*)edge_index)[(size_t)N_EDGES + e]
                : ((const uint32_t*)edge_index)[(size_t)N_EDGES + e];
            float2 gb = edge_attr[e];
            float2 u  = u_tab[dst];
            float vr = gb.x * u.x - gb.y * u.y;        // Re[(g-ib)conj(u)]
            float vi = -(gb.y * u.x + gb.x * u.y);     // Im[(g-ib)conj(u)]
            uint32_t nid = src_r[it];
            uint32_t bk = nid >> SHIFT, lid = nid & (SPAN - 1);
            uint32_t r = atomicAdd(&s_cnt[bk], 1u);
            uint2 rc;
            rc.x = (__float_as_uint(vr) & ~0xFFu) | lid;    // lid: 8 bits
            rc.y = (__float_as_uint(vi) & ~0x1FFu) | bk;    // bk: 9 bits
            s_rec[s_pref[bk] + r] = rc;
        }
    }
    __syncthreads();
    for (int b = tid; b < PREF_W; b += BTH)
        prefT[(size_t)b * NBLK + blk] = (uint16_t)s_pref[b];
    __threadfence();
    grid.sync();

    // ---------------- phase B: cross-block bases for owned buckets ----------
    {
        int nt = 0;
        for (int b = blk; b < NB; b += NBLK) {
            uint32_t lo = 0, cnt = 0;
            if (tid < NBLK) {
                lo  = prefT[(size_t)b * NBLK + tid];
                cnt = (uint32_t)prefT[(size_t)(b + 1) * NBLK + tid] - lo;
            }
            uint32_t x = cnt;                          // incl scan within wave
            #pragma unroll
            for (int off = 1; off < 64; off <<= 1) {
                uint32_t y = (uint32_t)__shfl_up((int)x, off, 64);
                if (lane >= off) x += y;
            }
            uint32_t ls = lo;                          // wave sum of lo
            #pragma unroll
            for (int off = 32; off > 0; off >>= 1)
                ls += (uint32_t)__shfl_down((int)ls, off, 64);
            if (tid < NBLK && lane == 63) s_wsum[wid] = x;
            if (tid < NBLK && lane == 0)  s_wsum[8 + wid] = ls;
            __syncthreads();
            if (tid == 0) {
                uint32_t S = s_wsum[8] + s_wsum[9] + s_wsum[10] + s_wsum[11];
                uint32_t c0 = s_wsum[0], c1 = s_wsum[1], c2 = s_wsum[2];
                s_woff[0] = 0u; s_woff[1] = c0; s_woff[2] = c0 + c1;
                s_woff[3] = c0 + c1 + c2;
                s_tS[nt] = S;
                s_tN[nt] = c0 + c1 + c2 + s_wsum[3];
            }
            __syncthreads();
            if (tid < NBLK)
                base_gT[(size_t)tid * NB + b] = s_tS[nt] + s_woff[wid] + (x - cnt);
            __syncthreads();
            ++nt;
        }
    }
    __threadfence();
    grid.sync();

    // ---------------- phase C: scatter LDS-sorted records to global --------
    for (int b = tid; b < NB; b += BTH)
        s_cnt[b] = base_gT[(size_t)blk * NB + b];      // base_row (coalesced)
    __syncthreads();
    for (int slot = tid; slot < CHUNK; slot += BTH) {
        uint2 rc = s_rec[slot];
        uint32_t bk = rc.y & 0x1FFu;
        uint32_t pos = s_cnt[bk] + ((uint32_t)slot - s_pref[bk]);
        gsorted[pos] = rc;
    }
    __threadfence();
    grid.sync();

    // ---------------- phase D: streaming reduce + loss ----------------
    {
        float loss = 0.0f;
        int nt = 0;
        for (int b = blk; b < NB; b += NBLK) {
            if (tid < SPAN) {
                #pragma unroll
                for (int r = 0; r < 4; ++r) s_acc[r][tid] = make_float2(0.f, 0.f);
            }
            __syncthreads();
            const uint32_t S = s_tS[nt], n = s_tN[nt];
            const int rep = wid & 3;
            for (uint32_t k = tid; k < n; k += BTH) {
                uint2 rc = gsorted[S + k];             // contiguous, coalesced
                uint32_t lid = rc.x & 0xFFu;
                atomicAdd(&s_acc[rep][lid].x, __uint_as_float(rc.x & ~0xFFu));
                atomicAdd(&s_acc[rep][lid].y, __uint_as_float(rc.y & ~0x1FFu));
            }
            __syncthreads();
            float v = 0.0f;
            int node = b * SPAN + tid;
            if (tid < SPAN && node < N_NODES) {
                float2 Sm = make_float2(0.f, 0.f);
                #pragma unroll
                for (int rr = 0; rr < 4; ++rr) {
                    float2 t = s_acc[rr][tid];
                    Sm.x += t.x; Sm.y += t.y;
                }
                float2 ui = u_tab[node];
                float2 bp = base_pq[node];
                float pc = ui.x * Sm.x - ui.y * Sm.y;  // Re(u*S)
                float qc = ui.x * Sm.y + ui.y * Sm.x;  // Im(u*S)
                float p = bp.x - pc, q = bp.y - qc;
                v = p * p + q * q;
            }
            #pragma unroll
            for (int off = 32; off > 0; off >>= 1) v += __shfl_down(v, off, 64);
            if (tid < SPAN && lane == 0) s_part[wid] = v;
            __syncthreads();
            if (tid == 0) loss += s_part[0] + s_part[1] + s_part[2] + s_part[3];
            __syncthreads();
            ++nt;
        }
        if (tid == 0) atomicAdd(d_out, loss * (1.0f / (float)N_NODES));
    }
}

// ---------------------------------------------------------------------------
extern "C" void kernel_launch(void* const* d_in, const int* in_sizes, int n_in,
                              void* d_out, int out_size, void* d_ws, size_t ws_size,
                              hipStream_t stream) {
    const float*  pred       = (const float*)d_in[0];
    const float*  target     = (const float*)d_in[1];
    const void*   edge_index = d_in[2];
    const float2* edge_attr  = (const float2*)d_in[3];
    const void*   mask       = d_in[4];
    float* out = (float*)d_out;

    char* ws = (char*)d_ws;
    float2*   u_tab   = (float2*)ws;                      //   800,000 B
    float2*   base_pq = (float2*)(ws + 800000);           //   800,000 B
    uint16_t* prefT   = (uint16_t*)(ws + 1600000);        //   200,704 B
    uint32_t* base_gT = (uint32_t*)(ws + 1800704);        //   400,384 B
    uint2*    gsorted = (uint2*)(ws + 2201088);           // 25,600,000 B  (~26.5 MB total)

    int out_size_v = out_size;
    void* args[] = {
        (void*)&pred, (void*)&target, (void*)&edge_index, (void*)&edge_attr,
        (void*)&mask, (void*)&u_tab, (void*)&base_pq, (void*)&prefT,
        (void*)&base_gT, (void*)&gsorted, (void*)&out, (void*)&out_size_v
    };
    hipLaunchCooperativeKernel((void*)fused_kernel, dim3(NBLK), dim3(BTH),
                               args, 0, stream);
}

// Round 14
// 169.786 us; speedup vs baseline: 3.9097x; 3.9097x over previous
//
#include <hip/hip_runtime.h>
#include <cstdint>

#define N_NODES 100000
#define N_EDGES 3200000
#define SPAN    256                              // nodes per bucket
#define SHIFT   8
#define NB      ((N_NODES + SPAN - 1) / SPAN)    // 391 buckets
#define CHUNK   8192                             // edges per bin block
#define BTH     1024
#define NITER   (CHUNK / BTH)                    // 8
#define NBLK    ((N_EDGES + CHUNK - 1) / CHUNK)  // 391 blocks
#define PREF_W  (NB + 1)                         // 392

// ---------------------------------------------------------------------------
// Kernel 1: per-node prep. Inline mask-dtype detect; u = vm*e^{i va};
// base = (pg-pd, qg-qd); zero d_out.
// ---------------------------------------------------------------------------
__global__ __launch_bounds__(256)
void prep_kernel(const float* __restrict__ pred,
                 const float* __restrict__ target,
                 const void* __restrict__ mask,
                 float2* __restrict__ u_tab,
                 float2* __restrict__ base_pq,
                 float* __restrict__ d_out, int out_size) {
    __shared__ int s_mask8;
    if (threadIdx.x < 64) {
        uint32_t w = ((const uint32_t*)mask)[threadIdx.x];
        bool nz = (w & 0xFFFFFF00u) != 0u;           // any off-aligned byte set
        unsigned long long m = __ballot(nz);
        if (threadIdx.x == 0) s_mask8 = (m != 0ull) ? 1 : 0;
    }
    if (blockIdx.x == 0 && threadIdx.x == 0)
        for (int k = 0; k < out_size; ++k) d_out[k] = 0.0f;
    __syncthreads();

    int i = blockIdx.x * 256 + threadIdx.x;
    if (i >= N_NODES) return;

    const float2* p2 = (const float2*)pred;
    const float2* t2 = (const float2*)target;
    float2 pa = p2[3 * i], pb = p2[3 * i + 1], pc = p2[3 * i + 2];
    float2 ta = t2[3 * i], tb = t2[3 * i + 1], tc = t2[3 * i + 2];
    float pr[6] = {pa.x, pa.y, pb.x, pb.y, pc.x, pc.y};
    float tg[6] = {ta.x, ta.y, tb.x, tb.y, tc.x, tc.y};
    int mk[6];
    if (s_mask8) {   // 1-byte bool
        const uint16_t* mu = (const uint16_t*)mask;
        uint16_t m0 = mu[3 * i], m1 = mu[3 * i + 1], m2 = mu[3 * i + 2];
        mk[0] = m0 & 0xFF; mk[1] = m0 >> 8;
        mk[2] = m1 & 0xFF; mk[3] = m1 >> 8;
        mk[4] = m2 & 0xFF; mk[5] = m2 >> 8;
    } else {         // int32
        const int2* mi = (const int2*)mask;
        int2 m0 = mi[3 * i], m1 = mi[3 * i + 1], m2 = mi[3 * i + 2];
        mk[0] = m0.x; mk[1] = m0.y; mk[2] = m1.x;
        mk[3] = m1.y; mk[4] = m2.x; mk[5] = m2.y;
    }
    float tp[6];
    #pragma unroll
    for (int j = 0; j < 6; ++j) tp[j] = mk[j] ? pr[j] : tg[j];

    float s, c;
    sincosf(tp[1], &s, &c);
    u_tab[i]   = make_float2(tp[0] * c, tp[0] * s);
    base_pq[i] = make_float2(tp[2] - tp[4], tp[3] - tp[5]);
}

// ---------------------------------------------------------------------------
// Kernel 2: bin. Per 8192-edge block (1024 thr): histogram (src+dst cached in
// regs) -> shfl scan -> 8 INDEPENDENT u_tab gathers in flight -> LDS counting
// sort -> streaming arena write (zero global atomics) + transposed u16 prefix.
// Record: rc.x = vr | lid (8 bits), rc.y = vi (exact).
// ---------------------------------------------------------------------------
__global__ __launch_bounds__(BTH)
void bin_kernel(const void* __restrict__ edge_index,
                const float2* __restrict__ edge_attr,
                const float2* __restrict__ u_tab,
                uint2* __restrict__ recs,           // [NBLK][CHUNK]
                uint16_t* __restrict__ pref_T) {    // [PREF_W][NBLK]
    __shared__ uint2 s_rec[CHUNK];         // 64 KB
    __shared__ uint32_t s_cnt[NB];         // counts, then running ranks
    __shared__ uint32_t s_pref[PREF_W];    // exclusive prefix
    __shared__ uint32_t s_wsum[16], s_woff[16];
    __shared__ int s_i64;

    const int tid = threadIdx.x;
    const int lane = tid & 63, wid = tid >> 6;     // 16 waves
    if (tid < 64) {
        uint32_t w = ((const uint32_t*)edge_index)[tid];
        bool nz = (tid & 1) && (w != 0u);  // odd word nonzero -> int32
        unsigned long long m = __ballot(nz);
        if (tid == 0) s_i64 = (m == 0ull) ? 1 : 0;
    }
    if (tid < NB) s_cnt[tid] = 0u;
    __syncthreads();
    const bool is64 = (s_i64 != 0);
    const long long ebase = (long long)blockIdx.x * CHUNK;
    const int nE = min(CHUNK, (int)(N_EDGES - ebase));

    // pass 1: histogram; cache src AND dst ids in registers (dst stream was
    // going to be read anyway — moving it here makes pass-2 gathers independent)
    uint32_t src_r[NITER], dst_r[NITER];
    #pragma unroll
    for (int it = 0; it < NITER; ++it) {
        int j = it * BTH + tid;
        uint32_t s = 0u, d = 0u;
        if (j < nE) {
            long long e = ebase + j;
            if (is64) {
                s = (uint32_t)((const unsigned long long*)edge_index)[e];
                d = (uint32_t)((const unsigned long long*)edge_index)[(size_t)N_EDGES + e];
            } else {
                s = ((const uint32_t*)edge_index)[e];
                d = ((const uint32_t*)edge_index)[(size_t)N_EDGES + e];
            }
            atomicAdd(&s_cnt[s >> SHIFT], 1u);
        }
        src_r[it] = s; dst_r[it] = d;
    }
    __syncthreads();

    // two-level shfl scan over 1024 slots (NB=391 live)
    {
        uint32_t v0 = (tid < NB) ? s_cnt[tid] : 0u;
        uint32_t x = v0;
        #pragma unroll
        for (int off = 1; off < 64; off <<= 1) {
            uint32_t y = (uint32_t)__shfl_up((int)x, off, 64);
            if (lane >= off) x += y;
        }
        if (lane == 63) s_wsum[wid] = x;
        __syncthreads();
        if (tid < 16) {
            uint32_t w0 = s_wsum[tid];
            uint32_t xx = w0;
            #pragma unroll
            for (int off = 1; off < 16; off <<= 1) {
                uint32_t y = (uint32_t)__shfl_up((int)xx, off, 64);
                if (tid >= off) xx += y;
            }
            s_woff[tid] = xx - w0;         // exclusive wave offset
        }
        __syncthreads();
        uint32_t incl = x + s_woff[wid];
        if (tid < NB) s_pref[tid + 1] = incl;
        if (tid == 0) s_pref[0] = 0u;
        if (tid < NB) s_cnt[tid] = 0u;     // reuse as running rank
        __syncthreads();
    }

    // pass 2a: issue ALL u gathers unconditionally -> 8 independent loads in flight
    float2 u_r[NITER];
    #pragma unroll
    for (int it = 0; it < NITER; ++it)
        u_r[it] = u_tab[dst_r[it]];        // dst_r = 0 for tail lanes: safe

    // pass 2b: compute record, place bucket-sorted in LDS
    #pragma unroll
    for (int it = 0; it < NITER; ++it) {
        int j = it * BTH + tid;
        if (j < nE) {
            float2 gb = edge_attr[ebase + j];
            float2 u  = u_r[it];
            float vr = gb.x * u.x - gb.y * u.y;        // Re[(g-ib)conj(u)]
            float vi = -(gb.y * u.x + gb.x * u.y);     // Im[(g-ib)conj(u)]
            uint32_t nid = src_r[it];
            uint32_t bk = nid >> SHIFT, lid = nid & (SPAN - 1);
            uint32_t r = atomicAdd(&s_cnt[bk], 1u);    // intra-block rank
            uint2 rc;
            rc.x = (__float_as_uint(vr) & ~0xFFu) | lid;    // lid: 8 bits
            rc.y = __float_as_uint(vi);                     // exact
            s_rec[s_pref[bk] + r] = rc;
        }
    }
    __syncthreads();

    // streaming arena write: fully coalesced uint4 copy (nE always even)
    {
        const uint4* s4 = (const uint4*)s_rec;
        uint4* a4 = (uint4*)(recs + (size_t)blockIdx.x * CHUNK);
        for (int k = tid; k < nE / 2; k += BTH) a4[k] = s4[k];
    }
    // transposed u16 prefix row (scattered 2B stores, fire-and-forget)
    for (int b = tid; b < PREF_W; b += BTH)
        pref_T[(size_t)b * NBLK + blockIdx.x] = (uint16_t)s_pref[b];
}

// ---------------------------------------------------------------------------
// Kernel 3: reduce. One 1024-thread block per bucket b. Threads t and t+NBLK
// process the two halves of producer-t's run; 2-deep software-pipelined uint4
// loads (prefetch next while processing current); LDS f32 accumulate (4 reps).
// ---------------------------------------------------------------------------
__global__ __launch_bounds__(1024)
void reduce_kernel(const uint2* __restrict__ recs,
                   const uint16_t* __restrict__ pref_T,
                   const float2* __restrict__ u_tab,
                   const float2* __restrict__ base_pq,
                   float* __restrict__ d_out) {
    __shared__ float2 s_acc[4][SPAN];      // 8 KB
    __shared__ float s_part[16];
    if (threadIdx.x < SPAN) {
        #pragma unroll
        for (int r = 0; r < 4; ++r) s_acc[r][threadIdx.x] = make_float2(0.0f, 0.0f);
    }
    __syncthreads();

    const int b = blockIdx.x;
    const int rep = (threadIdx.x >> 6) & 3;
    if (threadIdx.x < 2 * NBLK) {
        const int prod = (threadIdx.x < NBLK) ? threadIdx.x : threadIdx.x - NBLK;
        const int half = (threadIdx.x < NBLK) ? 0 : 1;
        uint32_t s0 = pref_T[(size_t)b * NBLK + prod];
        uint32_t e0 = pref_T[(size_t)(b + 1) * NBLK + prod];
        uint32_t mid = s0 + ((e0 - s0 + 1) >> 1);
        uint32_t j = half ? mid : s0;
        uint32_t e = half ? e0 : mid;
        const uint2* arena = recs + (size_t)prod * CHUNK;
        if (j < e && (j & 1)) {            // align to 16B
            uint2 rc = arena[j++];
            atomicAdd(&s_acc[rep][rc.x & 0xFFu].x, __uint_as_float(rc.x & ~0xFFu));
            atomicAdd(&s_acc[rep][rc.x & 0xFFu].y, __uint_as_float(rc.y));
        }
        if (j + 2 <= e) {
            uint4 q = *(const uint4*)&arena[j];       // pipeline prime
            for (;;) {
                uint4 cur = q;
                uint32_t jn = j + 2;
                bool more = (jn + 2 <= e);
                if (more) q = *(const uint4*)&arena[jn];   // next load in flight
                atomicAdd(&s_acc[rep][cur.x & 0xFFu].x, __uint_as_float(cur.x & ~0xFFu));
                atomicAdd(&s_acc[rep][cur.x & 0xFFu].y, __uint_as_float(cur.y));
                atomicAdd(&s_acc[rep][cur.z & 0xFFu].x, __uint_as_float(cur.z & ~0xFFu));
                atomicAdd(&s_acc[rep][cur.z & 0xFFu].y, __uint_as_float(cur.w));
                j = jn;
                if (!more) break;
            }
        }
        if (j < e) {
            uint2 rc = arena[j];
            atomicAdd(&s_acc[rep][rc.x & 0xFFu].x, __uint_as_float(rc.x & ~0xFFu));
            atomicAdd(&s_acc[rep][rc.x & 0xFFu].y, __uint_as_float(rc.y));
        }
    }
    __syncthreads();

    float v = 0.0f;
    int node = b * SPAN + (int)threadIdx.x;
    if (threadIdx.x < SPAN && node < N_NODES) {
        float2 S = make_float2(0.0f, 0.0f);
        #pragma unroll
        for (int rr = 0; rr < 4; ++rr) {
            float2 t = s_acc[rr][threadIdx.x];
            S.x += t.x; S.y += t.y;
        }
        float2 ui = u_tab[node];
        float2 bp = base_pq[node];
        float pc = ui.x * S.x - ui.y * S.y;   // Re(u*S)
        float qc = ui.x * S.y + ui.y * S.x;   // Im(u*S)
        float p = bp.x - pc, q = bp.y - qc;
        v = p * p + q * q;
    }
    #pragma unroll
    for (int off = 32; off > 0; off >>= 1) v += __shfl_down(v, off, 64);
    if ((threadIdx.x & 63) == 0) s_part[threadIdx.x >> 6] = v;
    __syncthreads();
    if (threadIdx.x == 0) {
        float t = 0.0f;
        #pragma unroll
        for (int w = 0; w < 16; ++w) t += s_part[w];
        atomicAdd(d_out, t * (1.0f / (float)N_NODES));
    }
}

// ---------------------------------------------------------------------------
extern "C" void kernel_launch(void* const* d_in, const int* in_sizes, int n_in,
                              void* d_out, int out_size, void* d_ws, size_t ws_size,
                              hipStream_t stream) {
    const float*  pred       = (const float*)d_in[0];
    const float*  target     = (const float*)d_in[1];
    const void*   edge_index = d_in[2];
    const float2* edge_attr  = (const float2*)d_in[3];
    const void*   mask       = d_in[4];
    float* out = (float*)d_out;

    char* ws = (char*)d_ws;
    float2*   u_tab   = (float2*)ws;                      // 800,000 B
    float2*   base_pq = (float2*)(ws + 800000);           // 800,000 B
    uint16_t* pref_T  = (uint16_t*)(ws + 1600000);        // 392*391*2 = 306,544 B
    uint2*    recs    = (uint2*)(ws + 1906560);           // 391*8192*8 = 25,624,576 B

    prep_kernel<<<(N_NODES + 255) / 256, 256, 0, stream>>>(
        pred, target, mask, u_tab, base_pq, out, out_size);

    bin_kernel<<<NBLK, BTH, 0, stream>>>(
        edge_index, edge_attr, u_tab, recs, pref_T);

    reduce_kernel<<<NB, 1024, 0, stream>>>(
        recs, pref_T, u_tab, base_pq, out);
}